// Round 3
// baseline (1218.849 us; speedup 1.0000x reference)
//
#include <hip/hip_runtime.h>
#include <cmath>

typedef unsigned short ushort;
typedef unsigned int uint;

typedef ushort u16x8 __attribute__((ext_vector_type(8)));
typedef ushort u16x4 __attribute__((ext_vector_type(4)));
typedef _Float16 f16x8 __attribute__((ext_vector_type(8)));
typedef float  f32x4 __attribute__((ext_vector_type(4)));

#define DEVINL __device__ __forceinline__

// fp32 -> fp16 (RTN, single v_cvt_f16_f32)
DEVINL ushort f2h(float f){
  _Float16 h = (_Float16)f;
  return __builtin_bit_cast(ushort, h);
}
DEVINL float h2f(ushort u){ return (float)__builtin_bit_cast(_Float16, u); }
DEVINL f16x8 u2h8(u16x8 u){ return __builtin_bit_cast(f16x8, u); }

DEVINL f32x4 mfma16(f16x8 a, f16x8 b, f32x4 c){
  return __builtin_amdgcn_mfma_f32_16x16x32_f16(a, b, c, 0, 0, 0);
}

// ---------------- weight fp32 -> fp16 cast ----------------
__global__ void cvt_f16(const float* __restrict__ src, ushort* __restrict__ dst, int n){
  int i = (blockIdx.x*blockDim.x + threadIdx.x)*4;
  if (i < n){
    f32x4 v = *(const f32x4*)(src + i);
    u16x4 o;
    #pragma unroll
    for(int j=0;j<4;j++) o[j] = f2h(v[j]);
    *(u16x4*)(dst + i) = o;
  }
}

// ---------------- projection GEMM: C[32768,512] = X[32768,512] * W[512,512]^T + b ----------------
// MODE 0: write fp16 C.  MODE 2: write fp16 C and fp16 tanh(C).
// MODE 1: write C transposed per-batch: vT[b][d][s].
template<int MODE>
__global__ __launch_bounds__(256) void gemm_proj(
    const float* __restrict__ X, const ushort* __restrict__ Wb,
    const float* __restrict__ bias,
    ushort* __restrict__ out, ushort* __restrict__ outt, ushort* __restrict__ vT)
{
  __shared__ ushort Ab[128*64];
  __shared__ ushort Bb[128*64];
  const int t = threadIdx.x, lane = t&63, wid = t>>6;
  const int wr = wid>>1, wc = wid&1;
  const int rt = blockIdx.x, ct = blockIdx.y;

  f32x4 acc[4][4];
  #pragma unroll
  for(int i=0;i<4;i++)
    #pragma unroll
    for(int j=0;j<4;j++) acc[i][j] = (f32x4)0.0f;

  for(int ph=0; ph<8; ++ph){
    #pragma unroll
    for(int i=0;i<4;i++){
      int ci = i*256 + t;
      int row = ci>>3, off = ci&7;
      const float* gp = X + (size_t)(rt*128+row)*512 + ph*64 + off*8;
      f32x4 v0 = *(const f32x4*)gp;
      f32x4 v1 = *(const f32x4*)(gp+4);
      u16x8 o;
      #pragma unroll
      for(int j=0;j<4;j++){ o[j] = f2h(v0[j]); o[4+j] = f2h(v1[j]); }
      *(u16x8*)((char*)Ab + ((ci*16) ^ ((row&7)<<4))) = o;
    }
    #pragma unroll
    for(int i=0;i<4;i++){
      int ci = i*256 + t;
      int row = ci>>3, off = ci&7;
      u16x8 v = *(const u16x8*)(Wb + (size_t)(ct*128+row)*512 + ph*64 + off*8);
      *(u16x8*)((char*)Bb + ((ci*16) ^ ((row&7)<<4))) = v;
    }
    __syncthreads();
    #pragma unroll
    for(int sub=0; sub<2; ++sub){
      f16x8 a[4], b[4];
      #pragma unroll
      for(int mf=0; mf<4; mf++){
        int row = wr*64 + mf*16 + (lane&15);
        int byte_ = (row*128 + sub*64 + (lane>>4)*16) ^ ((row&7)<<4);
        a[mf] = u2h8(*(const u16x8*)((char*)Ab + byte_));
      }
      #pragma unroll
      for(int nf=0; nf<4; nf++){
        int row = wc*64 + nf*16 + (lane&15);
        int byte_ = (row*128 + sub*64 + (lane>>4)*16) ^ ((row&7)<<4);
        b[nf] = u2h8(*(const u16x8*)((char*)Bb + byte_));
      }
      #pragma unroll
      for(int mf=0; mf<4; mf++)
        #pragma unroll
        for(int nf=0; nf<4; nf++)
          acc[mf][nf] = mfma16(a[mf], b[nf], acc[mf][nf]);
    }
    __syncthreads();
  }

  #pragma unroll
  for(int nf=0; nf<4; nf++){
    int col = ct*128 + wc*64 + nf*16 + (lane&15);
    float bv = bias[col];
    #pragma unroll
    for(int mf=0; mf<4; mf++){
      int grow0 = rt*128 + wr*64 + mf*16 + (lane>>4)*4;
      if(MODE==0){
        #pragma unroll
        for(int r=0;r<4;r++){
          float val = acc[mf][nf][r] + bv;
          out[(size_t)(grow0+r)*512 + col] = f2h(val);
        }
      } else if(MODE==2){
        #pragma unroll
        for(int r=0;r<4;r++){
          float val = acc[mf][nf][r] + bv;
          size_t idx = (size_t)(grow0+r)*512 + col;
          out[idx] = f2h(val);
          outt[idx] = f2h(tanhf(val));
        }
      } else {
        u16x4 pk;
        #pragma unroll
        for(int r=0;r<4;r++) pk[r] = f2h(acc[mf][nf][r] + bv);
        int bb = grow0 >> 11, ss = grow0 & 2047;
        *(u16x4*)(vT + (size_t)(bb*512 + col)*2048 + ss) = pk;
      }
    }
  }
}

// ---------------- attention scores: raw scores -> d_out, online softmax stats ----------------
__global__ __launch_bounds__(512) void attn_scores(
  const ushort* __restrict__ qb,
  const ushort* __restrict__ kb, const ushort* __restrict__ tkb,
  float* __restrict__ attn, float* __restrict__ rowm, float* __restrict__ rowl)
{
  __shared__ ushort kbuf[64*128];
  __shared__ ushort tkbuf[64*128];
  const int t = threadIdx.x, lane = t&63, wid = t>>6;
  const int bid = blockIdx.x, b = bid&15, qt = bid>>4;
  const int qrow0 = qt*128 + wid*16;

  f16x8 qa[16], ta[16];
  {
    const ushort* qp = qb + (size_t)(b*2048 + qrow0 + (lane&15))*512 + (lane>>4)*8;
    #pragma unroll
    for(int ks=0;ks<16;ks++){
      u16x8 qv = *(const u16x8*)(qp + ks*32);
      qa[ks] = u2h8(qv);
      u16x8 tv;
      #pragma unroll
      for(int j=0;j<8;j++) tv[j] = f2h(tanhf(h2f(qv[j])));
      ta[ks] = u2h8(tv);
    }
  }
  float mrun[4], lrun[4];
  #pragma unroll
  for(int r=0;r<4;r++){ mrun[r] = -1e30f; lrun[r] = 0.f; }

  #pragma unroll 1
  for(int kt=0; kt<32; ++kt){
    f32x4 acc0[4], acc1[4];
    #pragma unroll
    for(int nf=0;nf<4;nf++){ acc0[nf]=(f32x4)0.f; acc1[nf]=(f32x4)0.f; }
    #pragma unroll
    for(int ph=0; ph<4; ++ph){
      #pragma unroll
      for(int i=0;i<2;i++){
        int c2 = i*512 + t;
        int row = c2>>4, off = c2&15;
        size_t src = (size_t)(b*2048 + kt*64 + row)*512 + ph*128 + off*8;
        *(u16x8*)((char*)kbuf  + ((c2*16) ^ ((row&7)<<4))) = *(const u16x8*)(kb  + src);
        *(u16x8*)((char*)tkbuf + ((c2*16) ^ ((row&7)<<4))) = *(const u16x8*)(tkb + src);
      }
      __syncthreads();
      #pragma unroll
      for(int sub=0; sub<4; ++sub){
        int ks = ph*4 + sub;
        #pragma unroll
        for(int nf=0; nf<4; nf++){
          int row = nf*16 + (lane&15);
          int byte_ = (row*256 + sub*64 + (lane>>4)*16) ^ ((row&7)<<4);
          f16x8 bk_ = u2h8(*(const u16x8*)((char*)kbuf  + byte_));
          f16x8 bt_ = u2h8(*(const u16x8*)((char*)tkbuf + byte_));
          acc0[nf] = mfma16(qa[ks], bk_, acc0[nf]);
          acc1[nf] = mfma16(ta[ks], bt_, acc1[nf]);
        }
      }
      __syncthreads();
    }
    float s[4][4];
    #pragma unroll
    for(int nf=0;nf<4;nf++)
      #pragma unroll
      for(int r=0;r<4;r++)
        s[nf][r] = acc0[nf][r] * ((acc1[nf][r] + 1.0f)*0.5f) * 0.044194173824159216f;

    #pragma unroll
    for(int r=0;r<4;r++){
      float m = fmaxf(fmaxf(s[0][r],s[1][r]), fmaxf(s[2][r],s[3][r]));
      #pragma unroll
      for(int d=1; d<16; d<<=1) m = fmaxf(m, __shfl_xor(m, d));
      float mnew = fmaxf(mrun[r], m);
      float es = 0.f;
      #pragma unroll
      for(int nf=0;nf<4;nf++) es += __expf(s[nf][r] - mnew);
      #pragma unroll
      for(int d=1; d<16; d<<=1) es += __shfl_xor(es, d);
      lrun[r] = lrun[r]*__expf(mrun[r]-mnew) + es;
      mrun[r] = mnew;
    }
    #pragma unroll
    for(int nf=0;nf<4;nf++){
      int col = kt*64 + nf*16 + (lane&15);
      #pragma unroll
      for(int r=0;r<4;r++){
        int grow = qrow0 + (lane>>4)*4 + r;
        attn[(size_t)(b*2048 + grow)*2048 + col] = s[nf][r];
      }
    }
  }
  if((lane&15)==0){
    #pragma unroll
    for(int r=0;r<4;r++){
      int grow = qrow0 + (lane>>4)*4 + r;
      rowm[b*2048 + grow] = mrun[r];
      rowl[b*2048 + grow] = lrun[r];
    }
  }
}

// ---------------- normalize weights (writeback) + q_hat = attn @ v ----------------
__global__ __launch_bounds__(512) void attn_pv(
  const float* __restrict__ rowm, const float* __restrict__ rowl,
  float* __restrict__ attn, const ushort* __restrict__ vT,
  ushort* __restrict__ qhb)
{
  __shared__ ushort vbuf[512*40]; // 80B padded stride per dim row
  const int t = threadIdx.x, lane = t&63, wid = t>>6;
  const int bid = blockIdx.x, b = bid&15, qt = bid>>4;
  const int qrow = b*2048 + qt*128 + wid*16 + (lane&15);
  const float mw = rowm[qrow];
  const float rlw = 1.0f / rowl[qrow];
  float* srow = attn + (size_t)qrow*2048 + (lane>>4)*8;

  f32x4 acc[32];
  #pragma unroll
  for(int nf=0;nf<32;nf++) acc[nf]=(f32x4)0.f;

  #pragma unroll 1
  for(int ks=0; ks<64; ++ks){
    f32x4 s0 = *(const f32x4*)(srow + ks*32);
    f32x4 s1 = *(const f32x4*)(srow + ks*32 + 4);
    f32x4 w0, w1;
    #pragma unroll
    for(int j=0;j<4;j++){ w0[j] = __expf(s0[j]-mw)*rlw; w1[j] = __expf(s1[j]-mw)*rlw; }
    *(f32x4*)(srow + ks*32)     = w0;
    *(f32x4*)(srow + ks*32 + 4) = w1;
    u16x8 af;
    #pragma unroll
    for(int j=0;j<4;j++){ af[j] = f2h(w0[j]); af[4+j] = f2h(w1[j]); }
    f16x8 afs = u2h8(af);

    __syncthreads();
    #pragma unroll
    for(int i=0;i<4;i++){
      int ci = i*512 + t;
      int dim = ci>>2, off = ci&3;
      *(u16x8*)((char*)vbuf + dim*80 + off*16) =
        *(const u16x8*)(vT + (size_t)(b*512 + dim)*2048 + ks*32 + off*8);
    }
    __syncthreads();
    #pragma unroll
    for(int nf=0; nf<32; nf++){
      int row = nf*16 + (lane&15);
      f16x8 bv = u2h8(*(const u16x8*)((char*)vbuf + row*80 + (lane>>4)*16));
      acc[nf] = mfma16(afs, bv, acc[nf]);
    }
  }
  #pragma unroll
  for(int nf=0; nf<32; nf++){
    int col = nf*16 + (lane&15);
    #pragma unroll
    for(int r=0;r<4;r++){
      int grow = qt*128 + wid*16 + (lane>>4)*4 + r;
      qhb[(size_t)(b*2048+grow)*512 + col] = f2h(acc[nf][r]);
    }
  }
}

// ---------------- shared 64-row x 256-col GEMM tile helper (K = nph*64) ----------------
DEVINL void gemm_tile(const ushort* __restrict__ A, const ushort* __restrict__ W,
                      int r0, int t, int nph, f32x4 acc[4][4],
                      ushort* Ab, ushort* Wb)
{
  const int lane = t&63, wid = t>>6, wc0 = wid*64;
  const int K = nph*64;
  for(int ph=0; ph<nph; ++ph){
    #pragma unroll
    for(int i=0;i<2;i++){
      int ci = i*256 + t;
      int row = ci>>3, off = ci&7;
      *(u16x8*)((char*)Ab + ((ci*16) ^ ((row&7)<<4))) =
        *(const u16x8*)(A + (size_t)(r0+row)*K + ph*64 + off*8);
    }
    #pragma unroll
    for(int i=0;i<8;i++){
      int ci = i*256 + t;
      int row = ci>>3, off = ci&7;
      *(u16x8*)((char*)Wb + ((ci*16) ^ ((row&7)<<4))) =
        *(const u16x8*)(W + (size_t)row*K + ph*64 + off*8);
    }
    __syncthreads();
    #pragma unroll
    for(int sub=0; sub<2; ++sub){
      f16x8 a[4], bfr[4];
      #pragma unroll
      for(int mf=0;mf<4;mf++){
        int row = mf*16 + (lane&15);
        int byte_ = (row*128 + sub*64 + (lane>>4)*16) ^ ((row&7)<<4);
        a[mf] = u2h8(*(const u16x8*)((char*)Ab + byte_));
      }
      #pragma unroll
      for(int nf=0;nf<4;nf++){
        int row = wc0 + nf*16 + (lane&15);
        int byte_ = (row*128 + sub*64 + (lane>>4)*16) ^ ((row&7)<<4);
        bfr[nf] = u2h8(*(const u16x8*)((char*)Wb + byte_));
      }
      #pragma unroll
      for(int mf=0;mf<4;mf++)
        #pragma unroll
        for(int nf=0;nf<4;nf++)
          acc[mf][nf] = mfma16(a[mf], bfr[nf], acc[mf][nf]);
    }
    __syncthreads();
  }
}

// ---------------- post projections: G_pre, E_pre, Q3 ----------------
__global__ __launch_bounds__(256) void post_gemms(
  const ushort* __restrict__ qb, const ushort* __restrict__ qhb,
  const ushort* __restrict__ W0b, const ushort* __restrict__ W1b,
  const ushort* __restrict__ W2b, const ushort* __restrict__ W3b,
  const float* __restrict__ b0, const float* __restrict__ b1,
  const float* __restrict__ b2, const float* __restrict__ b3,
  ushort* __restrict__ Gpre, ushort* __restrict__ Epre, ushort* __restrict__ Q3b)
{
  __shared__ ushort Ab[64*64];
  __shared__ ushort Wb[256*64];
  const int t = threadIdx.x, lane = t&63, wid = t>>6, wc0 = wid*64;
  const int r0 = blockIdx.x*64;
  f32x4 accA[4][4], accB[4][4];

  #pragma unroll
  for(int i=0;i<4;i++)
    #pragma unroll
    for(int j=0;j<4;j++) accA[i][j]=(f32x4)0.f;
  gemm_tile(qb, W0b, r0, t, 8, accA, Ab, Wb);

  #pragma unroll
  for(int i=0;i<4;i++)
    #pragma unroll
    for(int j=0;j<4;j++) accB[i][j]=(f32x4)0.f;
  gemm_tile(qhb, W1b, r0, t, 8, accB, Ab, Wb);

  #pragma unroll
  for(int nf=0;nf<4;nf++){
    int col = wc0 + nf*16 + (lane&15);
    float bv0 = b0[col], bv1 = b1[col];
    #pragma unroll
    for(int mf=0;mf<4;mf++)
      #pragma unroll
      for(int r=0;r<4;r++){
        int row = r0 + mf*16 + (lane>>4)*4 + r;
        float a0 = fmaxf(accA[mf][nf][r] + bv0, 0.f);
        float a1 = fmaxf(accB[mf][nf][r] + bv1, 0.f);
        Gpre[(size_t)row*256 + col] = f2h(fmaxf(a0 + a1, 0.f));
      }
  }

  #pragma unroll
  for(int i=0;i<4;i++)
    #pragma unroll
    for(int j=0;j<4;j++) accB[i][j]=(f32x4)0.f;
  gemm_tile(qhb, W2b, r0, t, 8, accB, Ab, Wb);
  #pragma unroll
  for(int nf=0;nf<4;nf++){
    int col = wc0 + nf*16 + (lane&15);
    float bv2 = b2[col];
    #pragma unroll
    for(int mf=0;mf<4;mf++)
      #pragma unroll
      for(int r=0;r<4;r++){
        int row = r0 + mf*16 + (lane>>4)*4 + r;
        Epre[(size_t)row*256 + col] = f2h(fmaxf(accB[mf][nf][r] + bv2, 0.f));
      }
  }

  #pragma unroll
  for(int i=0;i<4;i++)
    #pragma unroll
    for(int j=0;j<4;j++) accB[i][j]=(f32x4)0.f;
  gemm_tile(qb, W3b, r0, t, 8, accB, Ab, Wb);
  #pragma unroll
  for(int nf=0;nf<4;nf++){
    int col = wc0 + nf*16 + (lane&15);
    float bv3 = b3[col];
    #pragma unroll
    for(int mf=0;mf<4;mf++)
      #pragma unroll
      for(int r=0;r<4;r++){
        int row = r0 + mf*16 + (lane>>4)*4 + r;
        Q3b[(size_t)row*256 + col] = f2h(fmaxf(accB[mf][nf][r] + bv3, 0.f));
      }
  }
}

// ---------------- LayerNorm(g) * LayerNorm(e) ----------------
__global__ __launch_bounds__(256) void ln_mul(
  const ushort* __restrict__ Gpre, const ushort* __restrict__ Epre,
  const float* __restrict__ gG, const float* __restrict__ betaG,
  const float* __restrict__ gE, const float* __restrict__ betaE,
  ushort* __restrict__ geb)
{
  const int t = threadIdx.x, lane = t&63, wid = t>>6;
  const int row = blockIdx.x*4 + wid;
  const int base = row*256 + lane*4;
  u16x4 gv = *(const u16x4*)(Gpre + base);
  u16x4 ev = *(const u16x4*)(Epre + base);
  float x[4], y[4];
  float sx=0.f, sxx=0.f, sy=0.f, syy=0.f;
  #pragma unroll
  for(int j=0;j<4;j++){
    x[j]=h2f(gv[j]); y[j]=h2f(ev[j]);
    sx += x[j]; sxx += x[j]*x[j];
    sy += y[j]; syy += y[j]*y[j];
  }
  #pragma unroll
  for(int d=1; d<64; d<<=1){
    sx += __shfl_xor(sx, d); sxx += __shfl_xor(sxx, d);
    sy += __shfl_xor(sy, d); syy += __shfl_xor(syy, d);
  }
  const float inv = 1.0f/256.0f;
  float mux = sx*inv,  varx = sxx*inv - mux*mux, rsx = rsqrtf(varx + 1e-5f);
  float muy = sy*inv,  vary = syy*inv - muy*muy, rsy = rsqrtf(vary + 1e-5f);
  u16x4 o;
  #pragma unroll
  for(int j=0;j<4;j++){
    int c = lane*4 + j;
    float g = (x[j]-mux)*rsx*gG[c] + betaG[c];
    float e = (y[j]-muy)*rsy*gE[c] + betaE[c];
    o[j] = f2h(g*e);
  }
  *(u16x4*)(geb + base) = o;
}

// ---------------- final: c = relu(ge @ Wc^T + bc); out = q_out + c ----------------
__global__ __launch_bounds__(256) void final_out(
  const ushort* __restrict__ geb, const ushort* __restrict__ Wcb,
  const float* __restrict__ bc, const ushort* __restrict__ Q3b,
  float* __restrict__ out1)
{
  __shared__ ushort Ab[64*64];
  __shared__ ushort Wb[256*64];
  const int t = threadIdx.x, lane = t&63, wid = t>>6, wc0 = wid*64;
  const int r0 = blockIdx.x*64;
  f32x4 acc[4][4];
  #pragma unroll
  for(int i=0;i<4;i++)
    #pragma unroll
    for(int j=0;j<4;j++) acc[i][j]=(f32x4)0.f;
  gemm_tile(geb, Wcb, r0, t, 4, acc, Ab, Wb);
  #pragma unroll
  for(int nf=0;nf<4;nf++){
    int col = wc0 + nf*16 + (lane&15);
    float bv = bc[col];
    #pragma unroll
    for(int mf=0;mf<4;mf++)
      #pragma unroll
      for(int r=0;r<4;r++){
        int row = r0 + mf*16 + (lane>>4)*4 + r;
        float c = fmaxf(acc[mf][nf][r] + bv, 0.f);
        out1[(size_t)row*256 + col] = c + h2f(Q3b[(size_t)row*256 + col]);
      }
  }
}

// ---------------- launch ----------------
extern "C" void kernel_launch(void* const* d_in, const int* in_sizes, int n_in,
                              void* d_out, int out_size, void* d_ws, size_t ws_size,
                              hipStream_t stream) {
  (void)in_sizes; (void)n_in; (void)out_size; (void)ws_size;
  const float* x1 = (const float*)d_in[0];
  const float* x2 = (const float*)d_in[1];
  const float* Wq = (const float*)d_in[2];  const float* bq = (const float*)d_in[3];
  const float* Wk = (const float*)d_in[4];  const float* bk = (const float*)d_in[5];
  const float* Wv = (const float*)d_in[6];  const float* bv = (const float*)d_in[7];
  const float* W0 = (const float*)d_in[8];  const float* b0 = (const float*)d_in[9];
  const float* W1 = (const float*)d_in[10]; const float* b1 = (const float*)d_in[11];
  const float* W2 = (const float*)d_in[12]; const float* b2 = (const float*)d_in[13];
  const float* W3 = (const float*)d_in[14]; const float* b3 = (const float*)d_in[15];
  const float* gG = (const float*)d_in[16]; const float* betaG = (const float*)d_in[17];
  const float* gE = (const float*)d_in[18]; const float* betaE = (const float*)d_in[19];
  const float* Wc = (const float*)d_in[20]; const float* bc = (const float*)d_in[21];

  char* ws = (char*)d_ws;
  const size_t SZ1 = (size_t)32768*512*2;   // fp16 [32768][512]
  ushort* qb  = (ushort*)(ws + 0*SZ1);
  ushort* kb  = (ushort*)(ws + 1*SZ1);
  ushort* tkb = (ushort*)(ws + 2*SZ1);
  ushort* vT  = (ushort*)(ws + 3*SZ1);
  ushort* qhb = (ushort*)(ws + 4*SZ1);
  char* p6 = ws + 5*SZ1;
  const size_t SZO = (size_t)32768*256*2;   // fp16 [32768][256]
  ushort* Gpre = (ushort*)(p6 + 0*SZO);
  ushort* Epre = (ushort*)(p6 + 1*SZO);
  ushort* geb  = (ushort*)(p6 + 2*SZO);
  ushort* Q3b  = (ushort*)(p6 + 3*SZO);
  float* rowm = (float*)(p6 + 4*SZO);
  float* rowl = rowm + 32768;
  char* pw = p6 + 4*SZO + 2*32768*sizeof(float);
  ushort* Wqb = (ushort*)(pw + 0);
  ushort* Wkb = (ushort*)(pw + 524288);
  ushort* Wvb = (ushort*)(pw + 2*524288);
  ushort* W0b = (ushort*)(pw + 3*524288);
  ushort* W1b = (ushort*)(pw + 3*524288 + 262144);
  ushort* W2b = (ushort*)(pw + 3*524288 + 2*262144);
  ushort* W3b = (ushort*)(pw + 3*524288 + 3*262144);
  ushort* Wcb = (ushort*)(pw + 3*524288 + 4*262144);

  cvt_f16<<<256,256,0,stream>>>(Wq, Wqb, 262144);
  cvt_f16<<<256,256,0,stream>>>(Wk, Wkb, 262144);
  cvt_f16<<<256,256,0,stream>>>(Wv, Wvb, 262144);
  cvt_f16<<<128,256,0,stream>>>(W0, W0b, 131072);
  cvt_f16<<<128,256,0,stream>>>(W1, W1b, 131072);
  cvt_f16<<<128,256,0,stream>>>(W2, W2b, 131072);
  cvt_f16<<<128,256,0,stream>>>(W3, W3b, 131072);
  cvt_f16<<<64,256,0,stream>>>(Wc, Wcb, 65536);

  gemm_proj<0><<<dim3(256,4),256,0,stream>>>(x2, Wqb, bq, qb, nullptr, nullptr);
  gemm_proj<2><<<dim3(256,4),256,0,stream>>>(x1, Wkb, bk, kb, tkb, nullptr);
  gemm_proj<1><<<dim3(256,4),256,0,stream>>>(x1, Wvb, bv, nullptr, nullptr, vT);

  float* out1 = (float*)d_out;
  float* attnp = out1 + (size_t)16*2048*256;

  attn_scores<<<256,512,0,stream>>>(qb, kb, tkb, attnp, rowm, rowl);
  attn_pv<<<256,512,0,stream>>>(rowm, rowl, attnp, vT, qhb);

  post_gemms<<<512,256,0,stream>>>(qb, qhb, W0b, W1b, W2b, W3b,
                                   b0, b1, b2, b3, Gpre, Epre, Q3b);
  ln_mul<<<8192,256,0,stream>>>(Gpre, Epre, gG, betaG, gE, betaE, geb);
  final_out<<<512,256,0,stream>>>(geb, Wcb, bc, Q3b, out1);
}

// Round 8
// 1140.763 us; speedup vs baseline: 1.0684x; 1.0684x over previous
//
#include <hip/hip_runtime.h>
#include <cmath>

typedef unsigned short ushort;
typedef unsigned int uint;

typedef ushort u16x8 __attribute__((ext_vector_type(8)));
typedef ushort u16x4 __attribute__((ext_vector_type(4)));
typedef _Float16 f16x8 __attribute__((ext_vector_type(8)));
typedef float  f32x4 __attribute__((ext_vector_type(4)));

#define DEVINL __device__ __forceinline__

DEVINL ushort f2h(float f){
  _Float16 h = (_Float16)f;
  return __builtin_bit_cast(ushort, h);
}
DEVINL float h2f(ushort u){ return (float)__builtin_bit_cast(_Float16, u); }
DEVINL f16x8 u2h8(u16x8 u){ return __builtin_bit_cast(f16x8, u); }

DEVINL f32x4 mfma16(f16x8 a, f16x8 b, f32x4 c){
  return __builtin_amdgcn_mfma_f32_16x16x32_f16(a, b, c, 0, 0, 0);
}

// async global -> LDS, 16B per lane. Dest must be wave-linear (lane-consecutive).
DEVINL void gload16(const ushort* g, ushort* l){
  __builtin_amdgcn_global_load_lds((const __attribute__((address_space(1))) unsigned int*)g,
                                   (__attribute__((address_space(3))) unsigned int*)l, 16, 0, 0);
}

// ---------------- fused weight fp32 -> fp16 cast (one launch) ----------------
struct CvtArgs { const float* s[8]; ushort* d[8]; int cum[9]; };
__global__ void cvt_all(CvtArgs a){
  int q = blockIdx.x*256 + threadIdx.x;
  #pragma unroll
  for(int k=0;k<8;k++){
    if(q >= a.cum[k] && q < a.cum[k+1]){
      int i = (q - a.cum[k])*4;
      f32x4 v = *(const f32x4*)(a.s[k] + i);
      u16x4 o;
      #pragma unroll
      for(int j=0;j<4;j++) o[j] = f2h(v[j]);
      *(u16x4*)(a.d[k] + i) = o;
    }
  }
}

// ---------------- projection GEMM: C[32768,512] = X[32768,512] * W[512,512]^T + b ----------------
// MODE 0: write fp16 C.  MODE 2: write fp16 C and fp16 tanh(C).
// MODE 1: write C transposed per-batch: vT[b][d][s].
template<int MODE>
__global__ __launch_bounds__(256) void gemm_proj(
    const float* __restrict__ X, const ushort* __restrict__ Wb,
    const float* __restrict__ bias,
    ushort* __restrict__ out, ushort* __restrict__ outt, ushort* __restrict__ vT)
{
  __shared__ ushort Ab[128*64];
  __shared__ ushort Bb[128*64];
  const int t = threadIdx.x, lane = t&63, wid = t>>6;
  const int wr = wid>>1, wc = wid&1;
  const int rt = blockIdx.x, ct = blockIdx.y;

  f32x4 acc[4][4];
  #pragma unroll
  for(int i=0;i<4;i++)
    #pragma unroll
    for(int j=0;j<4;j++) acc[i][j] = (f32x4)0.0f;

  for(int ph=0; ph<8; ++ph){
    #pragma unroll
    for(int i=0;i<4;i++){
      int ci = i*256 + t;
      int row = ci>>3, off = ci&7;
      const float* gp = X + (size_t)(rt*128+row)*512 + ph*64 + off*8;
      f32x4 v0 = *(const f32x4*)gp;
      f32x4 v1 = *(const f32x4*)(gp+4);
      u16x8 o;
      #pragma unroll
      for(int j=0;j<4;j++){ o[j] = f2h(v0[j]); o[4+j] = f2h(v1[j]); }
      *(u16x8*)((char*)Ab + ((ci*16) ^ ((row&7)<<4))) = o;
    }
    #pragma unroll
    for(int i=0;i<4;i++){
      int ci = i*256 + t;
      int row = ci>>3, off = ci&7;
      u16x8 v = *(const u16x8*)(Wb + (size_t)(ct*128+row)*512 + ph*64 + off*8);
      *(u16x8*)((char*)Bb + ((ci*16) ^ ((row&7)<<4))) = v;
    }
    __syncthreads();
    #pragma unroll
    for(int sub=0; sub<2; ++sub){
      f16x8 a[4], b[4];
      #pragma unroll
      for(int mf=0; mf<4; mf++){
        int row = wr*64 + mf*16 + (lane&15);
        int byte_ = (row*128 + sub*64 + (lane>>4)*16) ^ ((row&7)<<4);
        a[mf] = u2h8(*(const u16x8*)((char*)Ab + byte_));
      }
      #pragma unroll
      for(int nf=0; nf<4; nf++){
        int row = wc*64 + nf*16 + (lane&15);
        int byte_ = (row*128 + sub*64 + (lane>>4)*16) ^ ((row&7)<<4);
        b[nf] = u2h8(*(const u16x8*)((char*)Bb + byte_));
      }
      #pragma unroll
      for(int mf=0; mf<4; mf++)
        #pragma unroll
        for(int nf=0; nf<4; nf++)
          acc[mf][nf] = mfma16(a[mf], b[nf], acc[mf][nf]);
    }
    __syncthreads();
  }

  #pragma unroll
  for(int nf=0; nf<4; nf++){
    int col = ct*128 + wc*64 + nf*16 + (lane&15);
    float bv = bias[col];
    #pragma unroll
    for(int mf=0; mf<4; mf++){
      int grow0 = rt*128 + wr*64 + mf*16 + (lane>>4)*4;
      if(MODE==0){
        #pragma unroll
        for(int r=0;r<4;r++){
          float val = acc[mf][nf][r] + bv;
          out[(size_t)(grow0+r)*512 + col] = f2h(val);
        }
      } else if(MODE==2){
        #pragma unroll
        for(int r=0;r<4;r++){
          float val = acc[mf][nf][r] + bv;
          size_t idx = (size_t)(grow0+r)*512 + col;
          out[idx] = f2h(val);
          outt[idx] = f2h(tanhf(val));
        }
      } else {
        u16x4 pk;
        #pragma unroll
        for(int r=0;r<4;r++) pk[r] = f2h(acc[mf][nf][r] + bv);
        int bb = grow0 >> 11, ss = grow0 & 2047;
        *(u16x4*)(vT + (size_t)(bb*512 + col)*2048 + ss) = pk;
      }
    }
  }
}

// ---------------- attention scores v2: dbuf + global_load_lds + per-lane online softmax ----------------
__global__ __launch_bounds__(512) void attn_scores(
  const ushort* __restrict__ qb,
  const ushort* __restrict__ kb, const ushort* __restrict__ tkb,
  float* __restrict__ attn, float* __restrict__ rowm, float* __restrict__ rowl)
{
  __shared__ ushort kbuf[2][64*128];
  __shared__ ushort tkbuf[2][64*128];
  const int t = threadIdx.x, lane = t&63, wid = t>>6;
  const int bid = blockIdx.x, b = bid&15, qt = bid>>4;
  const int qrow0 = qt*128 + wid*16;

  // q (+tanh q) fragments in registers: 16 rows x 512 dims per wave
  f16x8 qa[16], ta[16];
  {
    const ushort* qp = qb + (size_t)(b*2048 + qrow0 + (lane&15))*512 + (lane>>4)*8;
    #pragma unroll
    for(int ks=0;ks<16;ks++){
      u16x8 qv = *(const u16x8*)(qp + ks*32);
      qa[ks] = u2h8(qv);
      u16x8 tv;
      #pragma unroll
      for(int j=0;j<8;j++) tv[j] = f2h(tanhf(h2f(qv[j])));
      ta[ks] = u2h8(tv);
    }
  }

  // staging geometry: 2 chunks/thread/array. chunk c2 = i*512+t; row=c2>>4, off=c2&15.
  // linear LDS dest granule c2; source column pre-swizzled: off ^ (row&7).
  const int row0 = t>>4, off0 = t&15;
  const int swz = (off0 ^ (row0&7))*8;            // same for chunk1 (row1=row0+32, row&7 equal)
  const ushort* kb_t0  = kb  + (size_t)(b*2048 + row0)*512 + swz;
  const ushort* tkb_t0 = tkb + (size_t)(b*2048 + row0)*512 + swz;
  const size_t c1off = (size_t)32*512;            // chunk1 source row offset
  const int d0 = t*8, d1 = (512+t)*8;             // LDS dest (ushort idx)

  float mrun[4], lrun[4];
  #pragma unroll
  for(int r=0;r<4;r++){ mrun[r] = -1e30f; lrun[r] = 0.f; }

  // prologue: stage (kt=0, ph=0) into buf 0
  {
    const size_t so = 0;
    gload16(kb_t0  + so, &kbuf[0][d0]);  gload16(kb_t0  + so + c1off, &kbuf[0][d1]);
    gload16(tkb_t0 + so, &tkbuf[0][d0]); gload16(tkb_t0 + so + c1off, &tkbuf[0][d1]);
  }
  __syncthreads();

  #pragma unroll 1
  for(int kt=0; kt<32; ++kt){
    f32x4 acc0[4], acc1[4];
    #pragma unroll
    for(int nf=0;nf<4;nf++){ acc0[nf]=(f32x4)0.f; acc1[nf]=(f32x4)0.f; }
    #pragma unroll
    for(int ph=0; ph<4; ++ph){
      const int cur = ph&1, nxt = cur^1;
      // stage next (kt,ph) tile while computing this one
      if(!(kt==31 && ph==3)){
        int nkt = (ph==3) ? kt+1 : kt;
        int nph = (ph==3) ? 0 : ph+1;
        const size_t so = (size_t)(nkt*64)*512 + nph*128;
        gload16(kb_t0  + so, &kbuf[nxt][d0]);  gload16(kb_t0  + so + c1off, &kbuf[nxt][d1]);
        gload16(tkb_t0 + so, &tkbuf[nxt][d0]); gload16(tkb_t0 + so + c1off, &tkbuf[nxt][d1]);
      }
      #pragma unroll
      for(int sub=0; sub<4; ++sub){
        int ks = ph*4 + sub;
        #pragma unroll
        for(int nf=0; nf<4; nf++){
          int row = nf*16 + (lane&15);
          int byte_ = (row*256 + sub*64 + (lane>>4)*16) ^ ((row&7)<<4);
          f16x8 bk_ = u2h8(*(const u16x8*)((char*)kbuf[cur]  + byte_));
          f16x8 bt_ = u2h8(*(const u16x8*)((char*)tkbuf[cur] + byte_));
          acc0[nf] = mfma16(qa[ks], bk_, acc0[nf]);
          acc1[nf] = mfma16(ta[ks], bt_, acc1[nf]);
        }
      }
      __syncthreads();   // drains vmcnt (stage landed) + all waves done reading cur
    }
    // finalize kt: raw scores, per-lane online stats (no cross-lane work here)
    float s[4][4];
    #pragma unroll
    for(int nf=0;nf<4;nf++)
      #pragma unroll
      for(int r=0;r<4;r++)
        s[nf][r] = acc0[nf][r] * ((acc1[nf][r] + 1.0f)*0.5f) * 0.044194173824159216f;

    #pragma unroll
    for(int r=0;r<4;r++){
      float mx = fmaxf(fmaxf(s[0][r],s[1][r]), fmaxf(s[2][r],s[3][r]));
      float mnew = fmaxf(mrun[r], mx);
      float es = 0.f;
      #pragma unroll
      for(int nf=0;nf<4;nf++) es += __expf(s[nf][r] - mnew);
      lrun[r] = lrun[r]*__expf(mrun[r]-mnew) + es;
      mrun[r] = mnew;
    }
    #pragma unroll
    for(int nf=0;nf<4;nf++){
      int col = kt*64 + nf*16 + (lane&15);
      #pragma unroll
      for(int r=0;r<4;r++){
        int grow = qrow0 + (lane>>4)*4 + r;
        attn[(size_t)(b*2048 + grow)*2048 + col] = s[nf][r];
      }
    }
  }

  // final cross-lane combine over the 16-lane row group
  #pragma unroll
  for(int r=0;r<4;r++){
    float m = mrun[r], l = lrun[r];
    #pragma unroll
    for(int d=1; d<16; d<<=1){
      float mo = __shfl_xor(m, d);
      float lo = __shfl_xor(l, d);
      float mn = fmaxf(m, mo);
      l = l*__expf(m-mn) + lo*__expf(mo-mn);
      m = mn;
    }
    mrun[r]=m; lrun[r]=l;
  }
  if((lane&15)==0){
    #pragma unroll
    for(int r=0;r<4;r++){
      int grow = qrow0 + (lane>>4)*4 + r;
      rowm[b*2048 + grow] = mrun[r];
      rowl[b*2048 + grow] = lrun[r];
    }
  }
}

// ---------------- attn_pv v2: normalize + q_hat with async-split pipeline ----------------
__global__ __launch_bounds__(512) void attn_pv(
  const float* __restrict__ rowm, const float* __restrict__ rowl,
  float* __restrict__ attn, const ushort* __restrict__ vT,
  ushort* __restrict__ qhb)
{
  __shared__ ushort vbuf[2][512*40]; // 80B padded stride per dim row
  const int t = threadIdx.x, lane = t&63, wid = t>>6;
  const int bid = blockIdx.x, b = bid&15, qt = bid>>4;
  const int qrow = b*2048 + qt*128 + wid*16 + (lane&15);
  const float mw = rowm[qrow];
  const float rlw = 1.0f / rowl[qrow];
  float* srow = attn + (size_t)qrow*2048 + (lane>>4)*8;

  // staging descriptors: 4 chunks/thread
  const ushort* vsrc[4];
  ushort *vd0[4], *vd1[4];
  #pragma unroll
  for(int i=0;i<4;i++){
    int ci = i*512 + t;
    int dim = ci>>2, off = ci&3;
    vsrc[i] = vT + (size_t)(b*512 + dim)*2048 + off*8;
    vd0[i] = &vbuf[0][dim*40 + off*8];
    vd1[i] = &vbuf[1][dim*40 + off*8];
  }

  f32x4 acc[32];
  #pragma unroll
  for(int nf=0;nf<32;nf++) acc[nf]=(f32x4)0.f;

  // prologue: V(0)->regs->buf0; V(1), S(0), S(1) in flight
  u16x8 vrA[4], vrB[4];
  f32x4 sA0, sA1, sB0, sB1;
  #pragma unroll
  for(int i=0;i<4;i++) vrA[i] = *(const u16x8*)(vsrc[i]);
  sA0 = *(const f32x4*)(srow);      sA1 = *(const f32x4*)(srow + 4);
  #pragma unroll
  for(int i=0;i<4;i++) vrB[i] = *(const u16x8*)(vsrc[i] + 32);
  sB0 = *(const f32x4*)(srow + 32); sB1 = *(const f32x4*)(srow + 36);
  #pragma unroll
  for(int i=0;i<4;i++) *(u16x8*)vd0[i] = vrA[i];
  __syncthreads();

  #pragma unroll 1
  for(int ks2=0; ks2<32; ++ks2){
    const int ks = ks2*2;
    // ---- even iter: compute buf0 with S=sA; V(ks+1)=vrB -> buf1; prefetch (ks+2) into A-set
    {
      #pragma unroll
      for(int i=0;i<4;i++) *(u16x8*)vd1[i] = vrB[i];
      if(ks+2 < 64){
        #pragma unroll
        for(int i=0;i<4;i++) vrA[i] = *(const u16x8*)(vsrc[i] + (size_t)(ks+2)*32);
      }
      f32x4 w0, w1;
      #pragma unroll
      for(int j=0;j<4;j++){ w0[j] = __expf(sA0[j]-mw)*rlw; w1[j] = __expf(sA1[j]-mw)*rlw; }
      *(f32x4*)(srow + ks*32)     = w0;
      *(f32x4*)(srow + ks*32 + 4) = w1;
      if(ks+2 < 64){
        sA0 = *(const f32x4*)(srow + (size_t)(ks+2)*32);
        sA1 = *(const f32x4*)(srow + (size_t)(ks+2)*32 + 4);
      }
      u16x8 af;
      #pragma unroll
      for(int j=0;j<4;j++){ af[j] = f2h(w0[j]); af[4+j] = f2h(w1[j]); }
      f16x8 afs = u2h8(af);
      #pragma unroll
      for(int nf=0; nf<32; nf++){
        int row = nf*16 + (lane&15);
        f16x8 bv = u2h8(*(const u16x8*)((char*)vbuf[0] + row*80 + (lane>>4)*16));
        acc[nf] = mfma16(afs, bv, acc[nf]);
      }
      __syncthreads();
    }
    // ---- odd iter: compute buf1 with S=sB; V(ks+2)=vrA -> buf0; prefetch (ks+3) into B-set
    {
      const int ko = ks+1;
      if(ko+1 < 64){
        #pragma unroll
        for(int i=0;i<4;i++) *(u16x8*)vd0[i] = vrA[i];
      }
      if(ko+2 < 64){
        #pragma unroll
        for(int i=0;i<4;i++) vrB[i] = *(const u16x8*)(vsrc[i] + (size_t)(ko+2)*32);
      }
      f32x4 w0, w1;
      #pragma unroll
      for(int j=0;j<4;j++){ w0[j] = __expf(sB0[j]-mw)*rlw; w1[j] = __expf(sB1[j]-mw)*rlw; }
      *(f32x4*)(srow + (size_t)ko*32)     = w0;
      *(f32x4*)(srow + (size_t)ko*32 + 4) = w1;
      if(ko+2 < 64){
        sB0 = *(const f32x4*)(srow + (size_t)(ko+2)*32);
        sB1 = *(const f32x4*)(srow + (size_t)(ko+2)*32 + 4);
      }
      u16x8 af;
      #pragma unroll
      for(int j=0;j<4;j++){ af[j] = f2h(w0[j]); af[4+j] = f2h(w1[j]); }
      f16x8 afs = u2h8(af);
      #pragma unroll
      for(int nf=0; nf<32; nf++){
        int row = nf*16 + (lane&15);
        f16x8 bv = u2h8(*(const u16x8*)((char*)vbuf[1] + row*80 + (lane>>4)*16));
        acc[nf] = mfma16(afs, bv, acc[nf]);
      }
      __syncthreads();
    }
  }

  #pragma unroll
  for(int nf=0; nf<32; nf++){
    int col = nf*16 + (lane&15);
    #pragma unroll
    for(int r=0;r<4;r++){
      int grow = qt*128 + wid*16 + (lane>>4)*4 + r;
      qhb[(size_t)(b*2048+grow)*512 + col] = f2h(acc[nf][r]);
    }
  }
}

// ---------------- shared 64-row x 256-col GEMM tile helper (K = nph*64) ----------------
DEVINL void gemm_tile(const ushort* __restrict__ A, const ushort* __restrict__ W,
                      int r0, int t, int nph, f32x4 acc[4][4],
                      ushort* Ab, ushort* Wb)
{
  const int lane = t&63, wid = t>>6, wc0 = wid*64;
  const int K = nph*64;
  for(int ph=0; ph<nph; ++ph){
    #pragma unroll
    for(int i=0;i<2;i++){
      int ci = i*256 + t;
      int row = ci>>3, off = ci&7;
      *(u16x8*)((char*)Ab + ((ci*16) ^ ((row&7)<<4))) =
        *(const u16x8*)(A + (size_t)(r0+row)*K + ph*64 + off*8);
    }
    #pragma unroll
    for(int i=0;i<8;i++){
      int ci = i*256 + t;
      int row = ci>>3, off = ci&7;
      *(u16x8*)((char*)Wb + ((ci*16) ^ ((row&7)<<4))) =
        *(const u16x8*)(W + (size_t)row*K + ph*64 + off*8);
    }
    __syncthreads();
    #pragma unroll
    for(int sub=0; sub<2; ++sub){
      f16x8 a[4], bfr[4];
      #pragma unroll
      for(int mf=0;mf<4;mf++){
        int row = mf*16 + (lane&15);
        int byte_ = (row*128 + sub*64 + (lane>>4)*16) ^ ((row&7)<<4);
        a[mf] = u2h8(*(const u16x8*)((char*)Ab + byte_));
      }
      #pragma unroll
      for(int nf=0;nf<4;nf++){
        int row = wc0 + nf*16 + (lane&15);
        int byte_ = (row*128 + sub*64 + (lane>>4)*16) ^ ((row&7)<<4);
        bfr[nf] = u2h8(*(const u16x8*)((char*)Wb + byte_));
      }
      #pragma unroll
      for(int mf=0;mf<4;mf++)
        #pragma unroll
        for(int nf=0;nf<4;nf++)
          acc[mf][nf] = mfma16(a[mf], bfr[nf], acc[mf][nf]);
    }
    __syncthreads();
  }
}

// ---------------- post projections: G_pre, E_pre, Q3 ----------------
__global__ __launch_bounds__(256) void post_gemms(
  const ushort* __restrict__ qb, const ushort* __restrict__ qhb,
  const ushort* __restrict__ W0b, const ushort* __restrict__ W1b,
  const ushort* __restrict__ W2b, const ushort* __restrict__ W3b,
  const float* __restrict__ b0, const float* __restrict__ b1,
  const float* __restrict__ b2, const float* __restrict__ b3,
  ushort* __restrict__ Gpre, ushort* __restrict__ Epre, ushort* __restrict__ Q3b)
{
  __shared__ ushort Ab[64*64];
  __shared__ ushort Wb[256*64];
  const int t = threadIdx.x, lane = t&63, wid = t>>6, wc0 = wid*64;
  const int r0 = blockIdx.x*64;
  f32x4 accA[4][4], accB[4][4];

  #pragma unroll
  for(int i=0;i<4;i++)
    #pragma unroll
    for(int j=0;j<4;j++) accA[i][j]=(f32x4)0.f;
  gemm_tile(qb, W0b, r0, t, 8, accA, Ab, Wb);

  #pragma unroll
  for(int i=0;i<4;i++)
    #pragma unroll
    for(int j=0;j<4;j++) accB[i][j]=(f32x4)0.f;
  gemm_tile(qhb, W1b, r0, t, 8, accB, Ab, Wb);

  #pragma unroll
  for(int nf=0;nf<4;nf++){
    int col = wc0 + nf*16 + (lane&15);
    float bv0 = b0[col], bv1 = b1[col];
    #pragma unroll
    for(int mf=0;mf<4;mf++)
      #pragma unroll
      for(int r=0;r<4;r++){
        int row = r0 + mf*16 + (lane>>4)*4 + r;
        float a0 = fmaxf(accA[mf][nf][r] + bv0, 0.f);
        float a1 = fmaxf(accB[mf][nf][r] + bv1, 0.f);
        Gpre[(size_t)row*256 + col] = f2h(fmaxf(a0 + a1, 0.f));
      }
  }

  #pragma unroll
  for(int i=0;i<4;i++)
    #pragma unroll
    for(int j=0;j<4;j++) accB[i][j]=(f32x4)0.f;
  gemm_tile(qhb, W2b, r0, t, 8, accB, Ab, Wb);
  #pragma unroll
  for(int nf=0;nf<4;nf++){
    int col = wc0 + nf*16 + (lane&15);
    float bv2 = b2[col];
    #pragma unroll
    for(int mf=0;mf<4;mf++)
      #pragma unroll
      for(int r=0;r<4;r++){
        int row = r0 + mf*16 + (lane>>4)*4 + r;
        Epre[(size_t)row*256 + col] = f2h(fmaxf(accB[mf][nf][r] + bv2, 0.f));
      }
  }

  #pragma unroll
  for(int i=0;i<4;i++)
    #pragma unroll
    for(int j=0;j<4;j++) accB[i][j]=(f32x4)0.f;
  gemm_tile(qb, W3b, r0, t, 8, accB, Ab, Wb);
  #pragma unroll
  for(int nf=0;nf<4;nf++){
    int col = wc0 + nf*16 + (lane&15);
    float bv3 = b3[col];
    #pragma unroll
    for(int mf=0;mf<4;mf++)
      #pragma unroll
      for(int r=0;r<4;r++){
        int row = r0 + mf*16 + (lane>>4)*4 + r;
        Q3b[(size_t)row*256 + col] = f2h(fmaxf(accB[mf][nf][r] + bv3, 0.f));
      }
  }
}

// ---------------- LayerNorm(g) * LayerNorm(e) ----------------
__global__ __launch_bounds__(256) void ln_mul(
  const ushort* __restrict__ Gpre, const ushort* __restrict__ Epre,
  const float* __restrict__ gG, const float* __restrict__ betaG,
  const float* __restrict__ gE, const float* __restrict__ betaE,
  ushort* __restrict__ geb)
{
  const int t = threadIdx.x, lane = t&63, wid = t>>6;
  const int row = blockIdx.x*4 + wid;
  const int base = row*256 + lane*4;
  u16x4 gv = *(const u16x4*)(Gpre + base);
  u16x4 ev = *(const u16x4*)(Epre + base);
  float x[4], y[4];
  float sx=0.f, sxx=0.f, sy=0.f, syy=0.f;
  #pragma unroll
  for(int j=0;j<4;j++){
    x[j]=h2f(gv[j]); y[j]=h2f(ev[j]);
    sx += x[j]; sxx += x[j]*x[j];
    sy += y[j]; syy += y[j]*y[j];
  }
  #pragma unroll
  for(int d=1; d<64; d<<=1){
    sx += __shfl_xor(sx, d); sxx += __shfl_xor(sxx, d);
    sy += __shfl_xor(sy, d); syy += __shfl_xor(syy, d);
  }
  const float inv = 1.0f/256.0f;
  float mux = sx*inv,  varx = sxx*inv - mux*mux, rsx = rsqrtf(varx + 1e-5f);
  float muy = sy*inv,  vary = syy*inv - muy*muy, rsy = rsqrtf(vary + 1e-5f);
  u16x4 o;
  #pragma unroll
  for(int j=0;j<4;j++){
    int c = lane*4 + j;
    float g = (x[j]-mux)*rsx*gG[c] + betaG[c];
    float e = (y[j]-muy)*rsy*gE[c] + betaE[c];
    o[j] = f2h(g*e);
  }
  *(u16x4*)(geb + base) = o;
}

// ---------------- final: c = relu(ge @ Wc^T + bc); out = q_out + c ----------------
__global__ __launch_bounds__(256) void final_out(
  const ushort* __restrict__ geb, const ushort* __restrict__ Wcb,
  const float* __restrict__ bc, const ushort* __restrict__ Q3b,
  float* __restrict__ out1)
{
  __shared__ ushort Ab[64*64];
  __shared__ ushort Wb[256*64];
  const int t = threadIdx.x, lane = t&63, wid = t>>6, wc0 = wid*64;
  const int r0 = blockIdx.x*64;
  f32x4 acc[4][4];
  #pragma unroll
  for(int i=0;i<4;i++)
    #pragma unroll
    for(int j=0;j<4;j++) acc[i][j]=(f32x4)0.f;
  gemm_tile(geb, Wcb, r0, t, 4, acc, Ab, Wb);
  #pragma unroll
  for(int nf=0;nf<4;nf++){
    int col = wc0 + nf*16 + (lane&15);
    float bv = bc[col];
    #pragma unroll
    for(int mf=0;mf<4;mf++)
      #pragma unroll
      for(int r=0;r<4;r++){
        int row = r0 + mf*16 + (lane>>4)*4 + r;
        float c = fmaxf(acc[mf][nf][r] + bv, 0.f);
        out1[(size_t)row*256 + col] = c + h2f(Q3b[(size_t)row*256 + col]);
      }
  }
}

// ---------------- launch ----------------
extern "C" void kernel_launch(void* const* d_in, const int* in_sizes, int n_in,
                              void* d_out, int out_size, void* d_ws, size_t ws_size,
                              hipStream_t stream) {
  (void)in_sizes; (void)n_in; (void)out_size; (void)ws_size;
  const float* x1 = (const float*)d_in[0];
  const float* x2 = (const float*)d_in[1];
  const float* Wq = (const float*)d_in[2];  const float* bq = (const float*)d_in[3];
  const float* Wk = (const float*)d_in[4];  const float* bk = (const float*)d_in[5];
  const float* Wv = (const float*)d_in[6];  const float* bv = (const float*)d_in[7];
  const float* W0 = (const float*)d_in[8];  const float* b0 = (const float*)d_in[9];
  const float* W1 = (const float*)d_in[10]; const float* b1 = (const float*)d_in[11];
  const float* W2 = (const float*)d_in[12]; const float* b2 = (const float*)d_in[13];
  const float* W3 = (const float*)d_in[14]; const float* b3 = (const float*)d_in[15];
  const float* gG = (const float*)d_in[16]; const float* betaG = (const float*)d_in[17];
  const float* gE = (const float*)d_in[18]; const float* betaE = (const float*)d_in[19];
  const float* Wc = (const float*)d_in[20]; const float* bc = (const float*)d_in[21];

  char* ws = (char*)d_ws;
  const size_t SZ1 = (size_t)32768*512*2;   // fp16 [32768][512]
  ushort* qb  = (ushort*)(ws + 0*SZ1);
  ushort* kb  = (ushort*)(ws + 1*SZ1);
  ushort* tkb = (ushort*)(ws + 2*SZ1);
  ushort* vT  = (ushort*)(ws + 3*SZ1);
  ushort* qhb = (ushort*)(ws + 4*SZ1);
  char* p6 = ws + 5*SZ1;
  const size_t SZO = (size_t)32768*256*2;   // fp16 [32768][256]
  ushort* Gpre = (ushort*)(p6 + 0*SZO);
  ushort* Epre = (ushort*)(p6 + 1*SZO);
  ushort* geb  = (ushort*)(p6 + 2*SZO);
  ushort* Q3b  = (ushort*)(p6 + 3*SZO);
  float* rowm = (float*)(p6 + 4*SZO);
  float* rowl = rowm + 32768;
  char* pw = p6 + 4*SZO + 2*32768*sizeof(float);
  ushort* Wqb = (ushort*)(pw + 0);
  ushort* Wkb = (ushort*)(pw + 524288);
  ushort* Wvb = (ushort*)(pw + 2*524288);
  ushort* W0b = (ushort*)(pw + 3*524288);
  ushort* W1b = (ushort*)(pw + 3*524288 + 262144);
  ushort* W2b = (ushort*)(pw + 3*524288 + 2*262144);
  ushort* W3b = (ushort*)(pw + 3*524288 + 3*262144);
  ushort* Wcb = (ushort*)(pw + 3*524288 + 4*262144);

  CvtArgs ca;
  ca.s[0]=Wq; ca.d[0]=Wqb; ca.s[1]=Wk; ca.d[1]=Wkb; ca.s[2]=Wv; ca.d[2]=Wvb;
  ca.s[3]=W0; ca.d[3]=W0b; ca.s[4]=W1; ca.d[4]=W1b; ca.s[5]=W2; ca.d[5]=W2b;
  ca.s[6]=W3; ca.d[6]=W3b; ca.s[7]=Wc; ca.d[7]=Wcb;
  int sizes4[8] = {65536,65536,65536,32768,32768,32768,32768,16384};
  int cum = 0;
  for(int k=0;k<8;k++){ ca.cum[k]=cum; cum += sizes4[k]; }
  ca.cum[8]=cum;
  cvt_all<<<cum/256,256,0,stream>>>(ca);

  gemm_proj<0><<<dim3(256,4),256,0,stream>>>(x2, Wqb, bq, qb, nullptr, nullptr);
  gemm_proj<2><<<dim3(256,4),256,0,stream>>>(x1, Wkb, bk, kb, tkb, nullptr);
  gemm_proj<1><<<dim3(256,4),256,0,stream>>>(x1, Wvb, bv, nullptr, nullptr, vT);

  float* out1 = (float*)d_out;
  float* attnp = out1 + (size_t)16*2048*256;

  attn_scores<<<256,512,0,stream>>>(qb, kb, tkb, attnp, rowm, rowl);
  attn_pv<<<256,512,0,stream>>>(rowm, rowl, attnp, vT, qhb);

  post_gemms<<<512,256,0,stream>>>(qb, qhb, W0b, W1b, W2b, W3b,
                                   b0, b1, b2, b3, Gpre, Epre, Q3b);
  ln_mul<<<8192,256,0,stream>>>(Gpre, Epre, gG, betaG, gE, betaE, geb);
  final_out<<<512,256,0,stream>>>(geb, Wcb, bc, Q3b, out1);
}